// Round 1
// baseline (205.574 us; speedup 1.0000x reference)
//
#include <hip/hip_runtime.h>
#include <math.h>

#define TSTEPS 200
#define NROTS  40      // 5*NQ*NL = 40 params per timestep circuit (2 layers)
#define DIM    16      // 2^NQ
#define BLK    256
#define DEG    3

// ---- gates on a 16-dim complex state held in registers -------------------
// Flat index: s = q0*8 + q1*4 + q2*2 + q3  (wire w -> bit (8>>w))

__device__ __forceinline__ void fsc(float h, float& s, float& c) {
    __sincosf(h, &s, &c);
}

template<int BIT>
__device__ __forceinline__ void g_rx(float* sr, float* si, float h) {
    float s, c; fsc(h, s, c);
    #pragma unroll
    for (int p = 0; p < DIM; ++p) {
        if (p & BIT) continue;
        const int q = p | BIT;
        float a0r = sr[p], a0i = si[p], a1r = sr[q], a1i = si[q];
        // [[c, -i s],[-i s, c]]
        sr[p] = c*a0r + s*a1i;
        si[p] = c*a0i - s*a1r;
        sr[q] = c*a1r + s*a0i;
        si[q] = c*a1i - s*a0r;
    }
}

template<int BIT>
__device__ __forceinline__ void g_ry(float* sr, float* si, float h) {
    float s, c; fsc(h, s, c);
    #pragma unroll
    for (int p = 0; p < DIM; ++p) {
        if (p & BIT) continue;
        const int q = p | BIT;
        float a0r = sr[p], a0i = si[p], a1r = sr[q], a1i = si[q];
        // [[c, -s],[s, c]]
        sr[p] = c*a0r - s*a1r;
        si[p] = c*a0i - s*a1i;
        sr[q] = s*a0r + c*a1r;
        si[q] = s*a0i + c*a1i;
    }
}

template<int BIT>
__device__ __forceinline__ void g_rz(float* sr, float* si, float h) {
    float s, c; fsc(h, s, c);
    #pragma unroll
    for (int p = 0; p < DIM; ++p) {
        float ar = sr[p], ai = si[p];
        if (p & BIT) { sr[p] = c*ar - s*ai; si[p] = c*ai + s*ar; }  // e^{+ih}
        else         { sr[p] = c*ar + s*ai; si[p] = c*ai - s*ar; }  // e^{-ih}
    }
}

template<int CBIT, int TBIT>
__device__ __forceinline__ void g_crx(float* sr, float* si, float h) {
    float s, c; fsc(h, s, c);
    #pragma unroll
    for (int p = 0; p < DIM; ++p) {
        if (!(p & CBIT) || (p & TBIT)) continue;   // control=1, target=0 half
        const int q = p | TBIT;
        float a0r = sr[p], a0i = si[p], a1r = sr[q], a1i = si[q];
        sr[p] = c*a0r + s*a1i;
        si[p] = c*a0i - s*a1r;
        sr[q] = c*a1r + s*a0i;
        si[q] = c*a1i - s*a0r;
    }
}

// One ansatz layer = 20 params: (RX,RY,RZ) per wire, CRX fwd ring, CRX bwd ring
__device__ __forceinline__ void apply_layer(float* sr, float* si, const float* pp) {
    g_rx<8>(sr, si, 0.5f*pp[0]);  g_ry<8>(sr, si, 0.5f*pp[1]);  g_rz<8>(sr, si, 0.5f*pp[2]);
    g_rx<4>(sr, si, 0.5f*pp[3]);  g_ry<4>(sr, si, 0.5f*pp[4]);  g_rz<4>(sr, si, 0.5f*pp[5]);
    g_rx<2>(sr, si, 0.5f*pp[6]);  g_ry<2>(sr, si, 0.5f*pp[7]);  g_rz<2>(sr, si, 0.5f*pp[8]);
    g_rx<1>(sr, si, 0.5f*pp[9]);  g_ry<1>(sr, si, 0.5f*pp[10]); g_rz<1>(sr, si, 0.5f*pp[11]);
    // forward ring: control i, target (i+1)%4
    g_crx<8,4>(sr, si, 0.5f*pp[12]);
    g_crx<4,2>(sr, si, 0.5f*pp[13]);
    g_crx<2,1>(sr, si, 0.5f*pp[14]);
    g_crx<1,8>(sr, si, 0.5f*pp[15]);
    // backward ring: i = 3..0, control i, target (i-1)%4
    g_crx<1,2>(sr, si, 0.5f*pp[16]);
    g_crx<2,4>(sr, si, 0.5f*pp[17]);
    g_crx<4,8>(sr, si, 0.5f*pp[18]);
    g_crx<8,1>(sr, si, 0.5f*pp[19]);
}

// One block per batch element b. Threads = timesteps (t >= TSTEPS contribute 0).
extern "C" __global__ void __launch_bounds__(BLK)
qac_kernel(const float* __restrict__ tp,    // (B, T, NROTS)
           const float* __restrict__ poly,  // (DEG+1,)
           const float* __restrict__ mixr,  // (T,)
           const float* __restrict__ mixi,  // (T,)
           const float* __restrict__ qff,   // (20,)
           float* __restrict__ out)         // (B, 12)
{
    __shared__ float  sp[TSTEPS * NROTS];          // 32 KB staged params
    __shared__ float2 s_part[BLK/64][DIM];
    __shared__ float2 s_work[DIM];
    __shared__ float2 s_acc[DIM];

    const int b   = blockIdx.x;
    const int tid = threadIdx.x;

    // coalesced stage of this batch's 8000 params into LDS (float4)
    const float4* g4 = (const float4*)(tp + (size_t)b * (TSTEPS * NROTS));
    float4* s4 = (float4*)sp;
    for (int i = tid; i < TSTEPS * NROTS / 4; i += BLK) s4[i] = g4[i];

    if (tid < DIM) {
        s_work[tid] = make_float2(tid == 0 ? 1.f : 0.f, 0.f);
        s_acc[tid]  = make_float2(tid == 0 ? poly[0] : 0.f, 0.f);
    }
    __syncthreads();

    const int t = tid;
    float cr_ = 0.f, ci_ = 0.f;
    if (t < TSTEPS) { cr_ = mixr[t]; ci_ = mixi[t]; }
    const float* myp = &sp[(t < TSTEPS ? t : TSTEPS - 1) * NROTS];

    for (int k = 1; k <= DEG; ++k) {
        float sr[DIM], si[DIM];
        #pragma unroll
        for (int i = 0; i < DIM; ++i) { float2 w = s_work[i]; sr[i] = w.x; si[i] = w.y; }

        apply_layer(sr, si, myp);
        apply_layer(sr, si, myp + 20);

        // scale by this timestep's LCU coefficient (0 for inactive lanes)
        #pragma unroll
        for (int i = 0; i < DIM; ++i) {
            float tr = sr[i]*cr_ - si[i]*ci_;
            si[i]    = sr[i]*ci_ + si[i]*cr_;
            sr[i]    = tr;
        }

        // wave-64 butterfly reduce (all lanes active, inactive-t lanes hold 0)
        #pragma unroll
        for (int off = 32; off >= 1; off >>= 1) {
            #pragma unroll
            for (int i = 0; i < DIM; ++i) {
                sr[i] += __shfl_xor(sr[i], off, 64);
                si[i] += __shfl_xor(si[i], off, 64);
            }
        }

        __syncthreads();                 // everyone done reading old s_work
        if ((tid & 63) == 0) {
            const int wv = tid >> 6;
            #pragma unroll
            for (int i = 0; i < DIM; ++i) s_part[wv][i] = make_float2(sr[i], si[i]);
        }
        __syncthreads();
        if (tid < DIM) {
            float wr = 0.f, wi = 0.f;
            #pragma unroll
            for (int wv = 0; wv < BLK/64; ++wv) { wr += s_part[wv][tid].x; wi += s_part[wv][tid].y; }
            s_work[tid] = make_float2(wr, wi);
            const float pk = poly[k];
            s_acc[tid].x += pk * wr;
            s_acc[tid].y += pk * wi;
        }
        __syncthreads();
    }

    // finalize: L1-scale, L2-normalize, qff ansatz (1 layer), expvals -> (12,)
    if (tid == 0) {
        float l1 = fabsf(poly[0]) + fabsf(poly[1]) + fabsf(poly[2]) + fabsf(poly[3]);
        float inv_l1 = 1.f / l1;
        float ar[DIM], ai[DIM];
        float n2 = 0.f;
        #pragma unroll
        for (int i = 0; i < DIM; ++i) {
            ar[i] = s_acc[i].x * inv_l1;
            ai[i] = s_acc[i].y * inv_l1;
            n2 += ar[i]*ar[i] + ai[i]*ai[i];
        }
        float scale = 1.f / (sqrtf(n2) + 1e-9f);
        #pragma unroll
        for (int i = 0; i < DIM; ++i) { ar[i] *= scale; ai[i] *= scale; }

        float q[20];
        #pragma unroll
        for (int i = 0; i < 20; ++i) q[i] = qff[i];
        apply_layer(ar, ai, q);

        float* o = out + (size_t)b * 12;
        #pragma unroll
        for (int qb = 0; qb < 4; ++qb) {
            const int bit = 8 >> qb;
            float X = 0.f, Y = 0.f, Z = 0.f;
            #pragma unroll
            for (int p = 0; p < DIM; ++p) {
                if (p & bit) continue;
                const int qq = p | bit;
                float a0r = ar[p], a0i = ai[p], a1r = ar[qq], a1i = ai[qq];
                X += 2.f * (a0r*a1r + a0i*a1i);
                Y += 2.f * (a0r*a1i - a0i*a1r);
                Z += a0r*a0r + a0i*a0i - a1r*a1r - a1i*a1i;
            }
            o[qb] = X; o[4 + qb] = Y; o[8 + qb] = Z;
        }
    }
}

extern "C" void kernel_launch(void* const* d_in, const int* in_sizes, int n_in,
                              void* d_out, int out_size, void* d_ws, size_t ws_size,
                              hipStream_t stream) {
    const float* tp   = (const float*)d_in[0];
    const float* poly = (const float*)d_in[1];
    const float* mixr = (const float*)d_in[2];
    const float* mixi = (const float*)d_in[3];
    const float* qff  = (const float*)d_in[4];
    float* out = (float*)d_out;
    const int B = in_sizes[0] / (TSTEPS * NROTS);   // 2048
    qac_kernel<<<dim3(B), dim3(BLK), 0, stream>>>(tp, poly, mixr, mixi, qff, out);
}